// Round 1
// baseline (20.818 us; speedup 1.0000x reference)
//
#include <hip/hip_runtime.h>

// Problem constants (fixed by the reference)
#define C8     8      // feat channels
#define KOBJ   32     // objects per image
#define BIMG   8      // batch
#define WW     128
#define HH     128
#define HWPIX  16384  // H*W
#define CWN    169    // conv params per object
#define GRIDX  16     // pixel tiles per (b,k): 16 * 256 * PIX = 16384
#define PIX    4      // pixels per thread
#define NBLK_PER_B (KOBJ * GRIDX)   // 512 partial slots per image

// Weight layout within the 169-vector (row-major reshapes):
//  c1w: [8][10] at 0..79   (in = 8 seg channels, x_rel, y_rel)
//  c1b: 80..87
//  c2w: [8][8]  at 88..151
//  c2b: 152..159
//  c3w: [8]     at 160..167
//  c3b: 168

__global__ __launch_bounds__(256) void mask_head_kernel(
    const float* __restrict__ seg_feat,    // [B,8,H,W]
    const float* __restrict__ conv_weight, // [B,169,H,W]
    const int* __restrict__ mask,          // [B,K]
    const long long* __restrict__ ind,     // [B,K]
    const float* __restrict__ target,      // [B,K,H,W]
    float* __restrict__ partial)           // [B*K*GRIDX][3]
{
    const int b    = blockIdx.z;
    const int k    = blockIdx.y;
    const int tile = blockIdx.x;
    const int t    = threadIdx.x;
    const int blockFlat = (b * KOBJ + k) * GRIDX + tile;
    float* my = partial + blockFlat * 3;

    // Masked-out objects contribute exactly zero to all sums.
    if (mask[b * KOBJ + k] == 0) {
        if (t == 0) { my[0] = 0.f; my[1] = 0.f; my[2] = 0.f; }
        return;
    }

    __shared__ float w[CWN];
    __shared__ float red[4][3];

    const int idx = (int)ind[b * KOBJ + k];
    if (t < CWN) {
        // gather: conv_weight[b, t, idx]
        w[t] = conv_weight[(b * CWN + t) * HWPIX + idx];
    }
    __syncthreads();

    const float cx = (float)(idx & (WW - 1));
    const float cy = (float)(idx >> 7);

    const float* seg = seg_feat + b * C8 * HWPIX;
    const float* tgt = target + (b * KOBJ + k) * HWPIX;

    const int p0 = tile * (256 * PIX) + t;

    // relative-coordinate channels
    float sx[PIX], sy[PIX];
#pragma unroll
    for (int i = 0; i < PIX; ++i) {
        const int p = p0 + i * 256;
        sx[i] = ((float)(p & (WW - 1)) - cx) * (1.0f / 128.0f);
        sy[i] = ((float)(p >> 7)       - cy) * (1.0f / 128.0f);
    }

    // seg features (coalesced per channel)
    float f[C8][PIX];
#pragma unroll
    for (int c = 0; c < C8; ++c)
#pragma unroll
        for (int i = 0; i < PIX; ++i)
            f[c][i] = seg[c * HWPIX + p0 + i * 256];

    // layer 1: 10 -> 8, relu
    float h1[C8][PIX];
#pragma unroll
    for (int o = 0; o < C8; ++o) {
        float acc[PIX];
        const float bias = w[80 + o];
#pragma unroll
        for (int i = 0; i < PIX; ++i) acc[i] = bias;
#pragma unroll
        for (int c = 0; c < C8; ++c) {
            const float wv = w[o * 10 + c];
#pragma unroll
            for (int i = 0; i < PIX; ++i) acc[i] = fmaf(wv, f[c][i], acc[i]);
        }
        const float wx = w[o * 10 + 8];
        const float wy = w[o * 10 + 9];
#pragma unroll
        for (int i = 0; i < PIX; ++i) {
            acc[i] = fmaf(wx, sx[i], acc[i]);
            acc[i] = fmaf(wy, sy[i], acc[i]);
            h1[o][i] = fmaxf(acc[i], 0.f);
        }
    }

    // layer 2: 8 -> 8, relu
    float h2[C8][PIX];
#pragma unroll
    for (int o = 0; o < C8; ++o) {
        float acc[PIX];
        const float bias = w[152 + o];
#pragma unroll
        for (int i = 0; i < PIX; ++i) acc[i] = bias;
#pragma unroll
        for (int c = 0; c < C8; ++c) {
            const float wv = w[88 + o * 8 + c];
#pragma unroll
            for (int i = 0; i < PIX; ++i) acc[i] = fmaf(wv, h1[c][i], acc[i]);
        }
#pragma unroll
        for (int i = 0; i < PIX; ++i) h2[o][i] = fmaxf(acc[i], 0.f);
    }

    // layer 3: 8 -> 1, sigmoid; fuse dice partial sums
    float z[PIX];
    const float b3 = w[168];
#pragma unroll
    for (int i = 0; i < PIX; ++i) z[i] = b3;
#pragma unroll
    for (int c = 0; c < C8; ++c) {
        const float wv = w[160 + c];
#pragma unroll
        for (int i = 0; i < PIX; ++i) z[i] = fmaf(wv, h2[c][i], z[i]);
    }

    float s_pt = 0.f, s_pp = 0.f, s_tt = 0.f;
#pragma unroll
    for (int i = 0; i < PIX; ++i) {
        const float pred = 1.0f / (1.0f + __expf(-z[i]));
        const float tv   = tgt[p0 + i * 256];
        s_pt = fmaf(pred, tv, s_pt);
        s_pp = fmaf(pred, pred, s_pp);
        s_tt = fmaf(tv, tv, s_tt);
    }

    // wave reduction (64-wide), then block reduction via LDS
#pragma unroll
    for (int off = 32; off > 0; off >>= 1) {
        s_pt += __shfl_down(s_pt, off);
        s_pp += __shfl_down(s_pp, off);
        s_tt += __shfl_down(s_tt, off);
    }
    const int wid = t >> 6;
    if ((t & 63) == 0) { red[wid][0] = s_pt; red[wid][1] = s_pp; red[wid][2] = s_tt; }
    __syncthreads();
    if (t == 0) {
        float a = 0.f, b2 = 0.f, c2 = 0.f;
#pragma unroll
        for (int i = 0; i < 4; ++i) { a += red[i][0]; b2 += red[i][1]; c2 += red[i][2]; }
        my[0] = a; my[1] = b2; my[2] = c2;
    }
}

__global__ __launch_bounds__(512) void finalize_kernel(
    const float* __restrict__ partial, float* __restrict__ out)
{
    const int t    = threadIdx.x;
    const int b    = t >> 6;   // one wave per image
    const int lane = t & 63;

    float pt = 0.f, pp = 0.f, tt = 0.f;
    for (int e = lane; e < NBLK_PER_B; e += 64) {
        const float* q = partial + (b * NBLK_PER_B + e) * 3;
        pt += q[0]; pp += q[1]; tt += q[2];
    }
#pragma unroll
    for (int off = 32; off > 0; off >>= 1) {
        pt += __shfl_down(pt, off);
        pp += __shfl_down(pp, off);
        tt += __shfl_down(tt, off);
    }
    __shared__ float per[BIMG];
    if (lane == 0) {
        per[b] = 1.0f - (2.0f * pt + 1.0f) / (pp + tt + 1.0f);
    }
    __syncthreads();
    if (t == 0) {
        float s = 0.f;
#pragma unroll
        for (int i = 0; i < BIMG; ++i) s += per[i];
        out[0] = s * (1.0f / (float)BIMG);
    }
}

extern "C" void kernel_launch(void* const* d_in, const int* in_sizes, int n_in,
                              void* d_out, int out_size, void* d_ws, size_t ws_size,
                              hipStream_t stream) {
    const float*     seg  = (const float*)d_in[0];
    const float*     cw   = (const float*)d_in[1];
    const int*       mask = (const int*)d_in[2];
    const long long* ind  = (const long long*)d_in[3];
    const float*     tgt  = (const float*)d_in[4];
    float* out     = (float*)d_out;
    float* partial = (float*)d_ws;   // BIMG*KOBJ*GRIDX*3 floats = 48 KiB

    dim3 grid(GRIDX, KOBJ, BIMG);
    mask_head_kernel<<<grid, 256, 0, stream>>>(seg, cw, mask, ind, tgt, partial);
    finalize_kernel<<<1, 512, 0, stream>>>(partial, out);
}

// Round 2
// 19.727 us; speedup vs baseline: 1.0553x; 1.0553x over previous
//
#include <hip/hip_runtime.h>

// Problem constants (fixed by the reference)
#define C8     8      // feat channels
#define KOBJ   32     // objects per image
#define BIMG   8      // batch
#define WW     128
#define HH     128
#define HWPIX  16384  // H*W
#define CWN    169    // conv params per object
#define PIX    8      // contiguous pixels per thread
#define GRIDX  8      // pixel tiles per (b,k): 8 * 256 * PIX = 16384
#define NBLK_PER_B (KOBJ * GRIDX)   // 256 partial slots per image

// Weight layout within the 169-vector (row-major reshapes):
//  c1w: [8][10] at 0..79   (in = 8 seg channels, x_rel, y_rel)
//  c1b: 80..87
//  c2w: [8][8]  at 88..151
//  c2b: 152..159
//  c3w: [8]     at 160..167
//  c3b: 168

__global__ __launch_bounds__(256) void mask_head_kernel(
    const float* __restrict__ seg_feat,    // [B,8,H,W]
    const float* __restrict__ conv_weight, // [B,169,H,W]
    const int* __restrict__ mask,          // [B,K]
    const long long* __restrict__ ind,     // [B,K]
    const float* __restrict__ target,      // [B,K,H,W]
    float* __restrict__ partial)           // [B*K*GRIDX][3]
{
    const int b    = blockIdx.z;
    const int k    = blockIdx.y;
    const int tile = blockIdx.x;
    const int t    = threadIdx.x;
    const int blockFlat = (b * KOBJ + k) * GRIDX + tile;
    float* my = partial + blockFlat * 3;

    // Masked-out objects contribute exactly zero to all sums.
    if (mask[b * KOBJ + k] == 0) {
        if (t == 0) { my[0] = 0.f; my[1] = 0.f; my[2] = 0.f; }
        return;
    }

    // Padded weight layout for broadcast ds_read_b128 (rows 16B-aligned).
    __shared__ __align__(16) float l1w[C8][12];  // [o][c], c<10 valid; [10..11] unused
    __shared__ __align__(16) float l2w[C8][C8];
    __shared__ __align__(16) float l1b[C8];
    __shared__ __align__(16) float l2b[C8];
    __shared__ __align__(16) float l3w[C8];
    __shared__ float l3b_s;
    __shared__ float red[4][3];

    const int idx = (int)ind[b * KOBJ + k];
    if (t < CWN) {
        const float v = conv_weight[(b * CWN + t) * HWPIX + idx];
        if (t < 80)       { l1w[t / 10][t % 10] = v; }
        else if (t < 88)  { l1b[t - 80] = v; }
        else if (t < 152) { const int u = t - 88; l2w[u >> 3][u & 7] = v; }
        else if (t < 160) { l2b[t - 152] = v; }
        else if (t < 168) { l3w[t - 160] = v; }
        else              { l3b_s = v; }
    }
    __syncthreads();

    const float cx = (float)(idx & (WW - 1));
    const float cy = (float)(idx >> 7);

    const float* seg = seg_feat + b * C8 * HWPIX;
    const float* tgt = target + (b * KOBJ + k) * HWPIX;

    const int p0 = (tile * 256 + t) * PIX;   // 8 contiguous pixels, same row

    // Prefetch target early (latency hidden under the MLP).
    const float4 t4a = *reinterpret_cast<const float4*>(&tgt[p0]);
    const float4 t4b = *reinterpret_cast<const float4*>(&tgt[p0 + 4]);

    // relative coordinates: same row for all 8 pixels
    const float sy  = ((float)(p0 >> 7) - cy) * (1.0f / 128.0f);
    const float sx0 = ((float)(p0 & (WW - 1)) - cx) * (1.0f / 128.0f);
    float sx[PIX];
#pragma unroll
    for (int i = 0; i < PIX; ++i) sx[i] = sx0 + (float)i * (1.0f / 128.0f);

    // seg features: 2x float4 per channel
    float f[C8][PIX];
#pragma unroll
    for (int c = 0; c < C8; ++c) {
        const float4 a = *reinterpret_cast<const float4*>(&seg[c * HWPIX + p0]);
        const float4 d = *reinterpret_cast<const float4*>(&seg[c * HWPIX + p0 + 4]);
        f[c][0] = a.x; f[c][1] = a.y; f[c][2] = a.z; f[c][3] = a.w;
        f[c][4] = d.x; f[c][5] = d.y; f[c][6] = d.z; f[c][7] = d.w;
    }

    // layer 1: 10 -> 8, relu   (wy*sy folded into per-o base)
    float h1[C8][PIX];
#pragma unroll
    for (int o = 0; o < C8; ++o) {
        const float4 wa = *reinterpret_cast<const float4*>(&l1w[o][0]);
        const float4 wb = *reinterpret_cast<const float4*>(&l1w[o][4]);
        const float4 wc = *reinterpret_cast<const float4*>(&l1w[o][8]); // .x=wx,.y=wy
        const float base = fmaf(wc.y, sy, l1b[o]);
#pragma unroll
        for (int i = 0; i < PIX; ++i) {
            float a = fmaf(wc.x, sx[i], base);
            a = fmaf(wa.x, f[0][i], a);
            a = fmaf(wa.y, f[1][i], a);
            a = fmaf(wa.z, f[2][i], a);
            a = fmaf(wa.w, f[3][i], a);
            a = fmaf(wb.x, f[4][i], a);
            a = fmaf(wb.y, f[5][i], a);
            a = fmaf(wb.z, f[6][i], a);
            a = fmaf(wb.w, f[7][i], a);
            h1[o][i] = fmaxf(a, 0.f);
        }
    }

    // layer 2: 8 -> 8, relu
    float h2[C8][PIX];
#pragma unroll
    for (int o = 0; o < C8; ++o) {
        const float4 wa = *reinterpret_cast<const float4*>(&l2w[o][0]);
        const float4 wb = *reinterpret_cast<const float4*>(&l2w[o][4]);
        const float bias = l2b[o];
#pragma unroll
        for (int i = 0; i < PIX; ++i) {
            float a = bias;
            a = fmaf(wa.x, h1[0][i], a);
            a = fmaf(wa.y, h1[1][i], a);
            a = fmaf(wa.z, h1[2][i], a);
            a = fmaf(wa.w, h1[3][i], a);
            a = fmaf(wb.x, h1[4][i], a);
            a = fmaf(wb.y, h1[5][i], a);
            a = fmaf(wb.z, h1[6][i], a);
            a = fmaf(wb.w, h1[7][i], a);
            h2[o][i] = fmaxf(a, 0.f);
        }
    }

    // layer 3: 8 -> 1, sigmoid; fuse dice partial sums
    const float4 wa = *reinterpret_cast<const float4*>(&l3w[0]);
    const float4 wb = *reinterpret_cast<const float4*>(&l3w[4]);
    const float b3 = l3b_s;
    float tv[PIX];
    tv[0] = t4a.x; tv[1] = t4a.y; tv[2] = t4a.z; tv[3] = t4a.w;
    tv[4] = t4b.x; tv[5] = t4b.y; tv[6] = t4b.z; tv[7] = t4b.w;

    float s_pt = 0.f, s_pp = 0.f, s_tt = 0.f;
#pragma unroll
    for (int i = 0; i < PIX; ++i) {
        float z = b3;
        z = fmaf(wa.x, h2[0][i], z);
        z = fmaf(wa.y, h2[1][i], z);
        z = fmaf(wa.z, h2[2][i], z);
        z = fmaf(wa.w, h2[3][i], z);
        z = fmaf(wb.x, h2[4][i], z);
        z = fmaf(wb.y, h2[5][i], z);
        z = fmaf(wb.z, h2[6][i], z);
        z = fmaf(wb.w, h2[7][i], z);
        const float e    = __expf(-z);
        const float pred = __builtin_amdgcn_rcpf(1.0f + e);
        s_pt = fmaf(pred, tv[i], s_pt);
        s_pp = fmaf(pred, pred, s_pp);
        s_tt = fmaf(tv[i], tv[i], s_tt);
    }

    // wave reduction (64-wide), then block reduction via LDS
#pragma unroll
    for (int off = 32; off > 0; off >>= 1) {
        s_pt += __shfl_down(s_pt, off);
        s_pp += __shfl_down(s_pp, off);
        s_tt += __shfl_down(s_tt, off);
    }
    const int wid = t >> 6;
    if ((t & 63) == 0) { red[wid][0] = s_pt; red[wid][1] = s_pp; red[wid][2] = s_tt; }
    __syncthreads();
    if (t == 0) {
        float a = 0.f, b2 = 0.f, c2 = 0.f;
#pragma unroll
        for (int i = 0; i < 4; ++i) { a += red[i][0]; b2 += red[i][1]; c2 += red[i][2]; }
        my[0] = a; my[1] = b2; my[2] = c2;
    }
}

__global__ __launch_bounds__(512) void finalize_kernel(
    const float* __restrict__ partial, float* __restrict__ out)
{
    const int t    = threadIdx.x;
    const int b    = t >> 6;   // one wave per image
    const int lane = t & 63;

    float pt = 0.f, pp = 0.f, tt = 0.f;
    for (int e = lane; e < NBLK_PER_B; e += 64) {
        const float* q = partial + (b * NBLK_PER_B + e) * 3;
        pt += q[0]; pp += q[1]; tt += q[2];
    }
#pragma unroll
    for (int off = 32; off > 0; off >>= 1) {
        pt += __shfl_down(pt, off);
        pp += __shfl_down(pp, off);
        tt += __shfl_down(tt, off);
    }
    __shared__ float per[BIMG];
    if (lane == 0) {
        per[b] = 1.0f - (2.0f * pt + 1.0f) / (pp + tt + 1.0f);
    }
    __syncthreads();
    if (t == 0) {
        float s = 0.f;
#pragma unroll
        for (int i = 0; i < BIMG; ++i) s += per[i];
        out[0] = s * (1.0f / (float)BIMG);
    }
}

extern "C" void kernel_launch(void* const* d_in, const int* in_sizes, int n_in,
                              void* d_out, int out_size, void* d_ws, size_t ws_size,
                              hipStream_t stream) {
    const float*     seg  = (const float*)d_in[0];
    const float*     cw   = (const float*)d_in[1];
    const int*       mask = (const int*)d_in[2];
    const long long* ind  = (const long long*)d_in[3];
    const float*     tgt  = (const float*)d_in[4];
    float* out     = (float*)d_out;
    float* partial = (float*)d_ws;   // BIMG*KOBJ*GRIDX*3 floats = 24 KiB

    dim3 grid(GRIDX, KOBJ, BIMG);
    mask_head_kernel<<<grid, 256, 0, stream>>>(seg, cw, mask, ind, tgt, partial);
    finalize_kernel<<<1, 512, 0, stream>>>(partial, out);
}